// Round 10
// baseline (465.191 us; speedup 1.0000x reference)
//
#include <hip/hip_runtime.h>

#define HH 192
#define WW 192
#define CC 64
#define NB 1024
#define SS 32

typedef __bf16 bf16x8 __attribute__((ext_vector_type(8)));
typedef float  f32x4  __attribute__((ext_vector_type(4)));

__device__ __forceinline__ unsigned short f2bf(float f) {
    unsigned int u = __builtin_bit_cast(unsigned int, f);
    u += 0x7FFFu + ((u >> 16) & 1u);   // round-to-nearest-even
    return (unsigned short)(u >> 16);
}

// ---------------------------------------------------------------------------
// Merged weight prep (single launch, 324 blocks x 256 thr):
//  blocks [0,144): conv1 w -> WT1;  [144,288): conv2 w -> WT2;
//  blocks [288,324): out w -> WTo (cols padded to 16).
// WT[tap][kc][nt][lane][j], c = kc*32 + (lane>>4)*8 + j, o = nt*16 + (lane&15)
// ---------------------------------------------------------------------------
__global__ __launch_bounds__(256) void wprep_kernel(
        const float* __restrict__ c1w, const float* __restrict__ c2w,
        const float* __restrict__ ow, unsigned short* __restrict__ wt1,
        unsigned short* __restrict__ wt2, unsigned short* __restrict__ wto) {
    int b = blockIdx.x;
    if (b < 288) {
        const float* w = (b < 144) ? c1w : c2w;
        unsigned short* wt = (b < 144) ? wt1 : wt2;
        int idx = (b < 144 ? b : b - 144) * 256 + threadIdx.x;   // 0 .. 36863
        int j    = idx & 7;
        int lane = (idx >> 3) & 63;
        int nt   = (idx >> 9) & 3;
        int kc   = (idx >> 11) & 1;
        int tap  = idx >> 12;
        int c = kc * 32 + ((lane >> 4) << 3) + j;
        int o = (nt << 4) + (lane & 15);
        wt[idx] = f2bf(w[(tap * 64 + c) * 64 + o]);
    } else {
        int idx = (b - 288) * 256 + threadIdx.x;                 // 0 .. 9215
        int j    = idx & 7;
        int lane = (idx >> 3) & 63;
        int kc   = (idx >> 9) & 1;
        int tap  = idx >> 10;
        int c = kc * 32 + ((lane >> 4) << 3) + j;
        int o = lane & 15;
        wto[idx] = (o < 3) ? f2bf(ow[(tap * 64 + c) * 3 + o]) : (unsigned short)0;
    }
}

// ---------------------------------------------------------------------------
// MEGA-FUSED crop -> conv1 -> conv2 -> outconv. One block per (8-out-row
// tile, box), 512 threads / 8 waves, NO intermediate global buffer.
//   Stage A: bilinear-gather crop rows y0-2 .. y0+11 (14 rows, zeros outside
//            [0,32)) into s_crop[14][32][64], XOR-swizzled (slot = cg^(px&7)).
//   Stage B: conv1 (SAME) rows y0-1..y0+10 (12 rows = 24 m-tiles, 3/wave)
//            -> ReLU -> s_c1[12][32][64] swizzled; rows outside [0,32)
//            written as ZERO (preserves conv2's SAME-padding semantics).
//   Stage C: conv2 (SAME) rows y0..y0+9 (10 rows = 20 m-tiles, mt = w+8i,
//            wave-uniform guard) -> ReLU -> back into s_crop rows 0..9.
//   Stage D: outconv (VALID, class-selected): wave w -> out row y0+w.
// LDS 57344+49152 = 104 KiB -> 1 blk/CU, 8 waves/CU (the proven L3-safe
// concurrency). launch_bounds(512,2) -> 256-VGPR budget, no spill (r8 lesson).
// Eliminates bufA entirely: 135 MB write + 90 MB fetch gone.
// ---------------------------------------------------------------------------
__global__ __launch_bounds__(512, 2) void mega_kernel(
        const float* __restrict__ feat, const float* __restrict__ boxes,
        const int* __restrict__ box_ids,
        const unsigned short* __restrict__ wt1, const float* __restrict__ c1b,
        const unsigned short* __restrict__ wt2, const float* __restrict__ c2b,
        const unsigned short* __restrict__ wto, const float* __restrict__ ob,
        const int* __restrict__ cls, float* __restrict__ out) {
    __shared__ unsigned short s_crop[14 * 32 * 64];   // 57344 B
    __shared__ unsigned short s_c1[12 * 32 * 64];     // 49152 B

    int gn = blockIdx.y;
    int y0 = blockIdx.x << 3;
    int t = threadIdx.x;
    int wave = t >> 6, lane = t & 63;
    int quad = lane >> 4, mcol = lane & 15;

    // ---- Stage A: crop gather, rows r=0..13 <-> gy = y0-2+r ----
    {
        int px = (t >> 3) & 31, cg = t & 7, sub = t >> 8, c0 = cg << 3;
        float by1 = boxes[gn * 4 + 0];
        float bx1 = boxes[gn * 4 + 1];
        float by2 = boxes[gn * 4 + 2];
        float bx2 = boxes[gn * 4 + 3];
        float tx = (float)px / 31.0f;
        float xsf = (bx1 + tx * (bx2 - bx1)) * 191.0f;
        float x0f = fminf(fmaxf(floorf(xsf), 0.0f), 191.0f);
        float wx = xsf - x0f;
        int x0i = (int)x0f, x1i = min(x0i + 1, 191);
        const float* fb = feat + (size_t)box_ids[gn] * (HH * WW * CC);
        unsigned short* dst = s_crop + (px << 6) + ((cg ^ (px & 7)) << 3);
#pragma unroll 2
        for (int i = 0; i < 7; i++) {
            int r = sub * 7 + i;
            int gy = y0 - 2 + r;
            uint4 v = {0, 0, 0, 0};
            if (gy >= 0 && gy < 32) {
                float ty = (float)gy / 31.0f;
                float ysf = (by1 + ty * (by2 - by1)) * 191.0f;
                float y0f = fminf(fmaxf(floorf(ysf), 0.0f), 191.0f);
                float wy = ysf - y0f;
                int y0i = (int)y0f, y1i = min(y0i + 1, 191);
                const float* p00 = fb + ((size_t)y0i * WW + x0i) * CC + c0;
                const float* p01 = fb + ((size_t)y0i * WW + x1i) * CC + c0;
                const float* p10 = fb + ((size_t)y1i * WW + x0i) * CC + c0;
                const float* p11 = fb + ((size_t)y1i * WW + x1i) * CC + c0;
                unsigned int rr[4];
#pragma unroll
                for (int h = 0; h < 2; h++) {
                    float4 v00 = *(const float4*)(p00 + 4 * h);
                    float4 v01 = *(const float4*)(p01 + 4 * h);
                    float4 v10 = *(const float4*)(p10 + 4 * h);
                    float4 v11 = *(const float4*)(p11 + 4 * h);
                    const float* a00 = (const float*)&v00;
                    const float* a01 = (const float*)&v01;
                    const float* a10 = (const float*)&v10;
                    const float* a11 = (const float*)&v11;
#pragma unroll
                    for (int e2 = 0; e2 < 4; e2++) {
                        float top = a00[e2] + wx * (a01[e2] - a00[e2]);
                        float bot = a10[e2] + wx * (a11[e2] - a10[e2]);
                        float val = top + wy * (bot - top);
                        unsigned short bb = f2bf(val);
                        int e = 4 * h + e2;
                        if (e & 1) rr[e >> 1] |= ((unsigned int)bb << 16);
                        else       rr[e >> 1]  = (unsigned int)bb;
                    }
                }
                v = *(uint4*)rr;
            }
            *(uint4*)(dst + (r << 11)) = v;
        }
    }
    __syncthreads();

    // ---- Stage B: conv1. 24 m-tiles (lr1 = mt>>1 in 0..11, half h = mt&1);
    //      wave w -> mt = 3w..3w+2. conv1 row lr1 reads s_crop rows lr1..lr1+2.
    {
        f32x4 acc1[3][4];
#pragma unroll
        for (int i = 0; i < 3; i++)
#pragma unroll
            for (int nt = 0; nt < 4; nt++) {
                float bv = c1b[(nt << 4) + mcol];
                acc1[i][nt] = (f32x4){bv, bv, bv, bv};
            }
#pragma unroll
        for (int dy = 0; dy < 3; dy++) {
#pragma unroll
            for (int dx = 0; dx < 3; dx++) {
                int tap = dy * 3 + dx;
#pragma unroll
                for (int kc = 0; kc < 2; kc++) {
                    int cslot = (kc << 2) + quad;
                    uint4 bfr[4];
#pragma unroll
                    for (int nt = 0; nt < 4; nt++)
                        bfr[nt] = *(const uint4*)(wt1 + ((((tap * 2 + kc) * 4 + nt) * 64 + lane) << 3));
#pragma unroll
                    for (int i = 0; i < 3; i++) {
                        int mt = wave * 3 + i;
                        int lr1 = mt >> 1, h = mt & 1;
                        int xs = (h << 4) + mcol + dx - 1;
                        uint4 a = {0, 0, 0, 0};
                        if (xs >= 0 && xs < 32)
                            a = *(const uint4*)(s_crop + (((lr1 + dy) * 32 + xs) << 6) +
                                                ((cslot ^ (xs & 7)) << 3));
#pragma unroll
                        for (int nt = 0; nt < 4; nt++)
                            acc1[i][nt] = __builtin_amdgcn_mfma_f32_16x16x32_bf16(
                                __builtin_bit_cast(bf16x8, a),
                                __builtin_bit_cast(bf16x8, bfr[nt]), acc1[i][nt], 0, 0, 0);
                    }
                }
            }
        }
        // write ReLU'd conv1 into s_c1 (swizzled); rows outside [0,32) -> ZERO
#pragma unroll
        for (int i = 0; i < 3; i++) {
            int mt = wave * 3 + i;
            int lr1 = mt >> 1, h = mt & 1;
            int g1 = y0 - 1 + lr1;
            bool ok = (g1 >= 0 && g1 < 32);
#pragma unroll
            for (int reg = 0; reg < 4; reg++) {
                int px = (h << 4) + (quad << 2) + reg;
#pragma unroll
                for (int nt = 0; nt < 4; nt++) {
                    int oc = (nt << 4) + mcol;
                    float v = ok ? fmaxf(acc1[i][nt][reg], 0.0f) : 0.0f;
                    s_c1[((lr1 * 32 + px) << 6) + (((oc >> 3) ^ (px & 7)) << 3) + (oc & 7)] = f2bf(v);
                }
            }
        }
    }
    __syncthreads();

    // ---- Stage C: conv2. 20 m-tiles (lr2 = mt>>1 in 0..9); mt = wave + 8i,
    //      wave-uniform guard mt<20. Reads s_c1 rows lr2..lr2+2; writes
    //      ReLU'd bf16 back into s_crop rows 0..9 (s_crop free after B).
    {
        f32x4 acc2[3][4];
#pragma unroll
        for (int i = 0; i < 3; i++)
#pragma unroll
            for (int nt = 0; nt < 4; nt++) {
                float bv = c2b[(nt << 4) + mcol];
                acc2[i][nt] = (f32x4){bv, bv, bv, bv};
            }
#pragma unroll
        for (int dy = 0; dy < 3; dy++) {
#pragma unroll
            for (int dx = 0; dx < 3; dx++) {
                int tap = dy * 3 + dx;
#pragma unroll
                for (int kc = 0; kc < 2; kc++) {
                    int cslot = (kc << 2) + quad;
                    uint4 bfr[4];
#pragma unroll
                    for (int nt = 0; nt < 4; nt++)
                        bfr[nt] = *(const uint4*)(wt2 + ((((tap * 2 + kc) * 4 + nt) * 64 + lane) << 3));
#pragma unroll
                    for (int i = 0; i < 3; i++) {
                        int mt = wave + (i << 3);
                        if (mt < 20) {                        // wave-uniform
                            int lr2 = mt >> 1, h = mt & 1;
                            int xs = (h << 4) + mcol + dx - 1;
                            uint4 a = {0, 0, 0, 0};
                            if (xs >= 0 && xs < 32)
                                a = *(const uint4*)(s_c1 + (((lr2 + dy) * 32 + xs) << 6) +
                                                    ((cslot ^ (xs & 7)) << 3));
#pragma unroll
                            for (int nt = 0; nt < 4; nt++)
                                acc2[i][nt] = __builtin_amdgcn_mfma_f32_16x16x32_bf16(
                                    __builtin_bit_cast(bf16x8, a),
                                    __builtin_bit_cast(bf16x8, bfr[nt]), acc2[i][nt], 0, 0, 0);
                        }
                    }
                }
            }
        }
#pragma unroll
        for (int i = 0; i < 3; i++) {
            int mt = wave + (i << 3);
            if (mt < 20) {
                int lr2 = mt >> 1, h = mt & 1;
#pragma unroll
                for (int reg = 0; reg < 4; reg++) {
                    int px = (h << 4) + (quad << 2) + reg;
#pragma unroll
                    for (int nt = 0; nt < 4; nt++) {
                        int oc = (nt << 4) + mcol;
                        float v = fmaxf(acc2[i][nt][reg], 0.0f);
                        s_crop[((lr2 * 32 + px) << 6) + (((oc >> 3) ^ (px & 7)) << 3) + (oc & 7)] = f2bf(v);
                    }
                }
            }
        }
    }
    __syncthreads();

    // ---- Stage D: outconv (VALID, class-selected). wave w -> out row y0+w,
    //      reads conv2 rows w..w+2 from s_crop (indices 0..9).
    {
        f32x4 acc3[2];
        acc3[0] = (f32x4){0.f, 0.f, 0.f, 0.f};
        acc3[1] = (f32x4){0.f, 0.f, 0.f, 0.f};
#pragma unroll
        for (int dy = 0; dy < 3; dy++) {
#pragma unroll
            for (int dx = 0; dx < 3; dx++) {
                int tap = dy * 3 + dx;
#pragma unroll
                for (int kc = 0; kc < 2; kc++) {
                    int cslot = (kc << 2) + quad;
                    uint4 bfr = *(const uint4*)(wto + (((tap * 2 + kc) * 64 + lane) << 3));
#pragma unroll
                    for (int mi = 0; mi < 2; mi++) {
                        int xs = (mi << 4) + mcol + dx;       // 0..33
                        if (xs > 31) xs = 31;                 // clamped lanes feed x>=30 (discarded)
                        uint4 a = *(const uint4*)(s_crop + (((wave + dy) * 32 + xs) << 6) +
                                                  ((cslot ^ (xs & 7)) << 3));
                        acc3[mi] = __builtin_amdgcn_mfma_f32_16x16x32_bf16(
                            __builtin_bit_cast(bf16x8, a),
                            __builtin_bit_cast(bf16x8, bfr), acc3[mi], 0, 0, 0);
                    }
                }
            }
        }
        int oc = cls[gn];
        int yy = y0 + wave;
        if (mcol == oc && yy < 30) {
            float obv = ob[oc];
#pragma unroll
            for (int mi = 0; mi < 2; mi++) {
                int xb = (mi << 4) + (quad << 2);
#pragma unroll
                for (int reg = 0; reg < 4; reg++) {
                    int x = xb + reg;
                    if (x < 30)
                        out[(size_t)gn * 900 + yy * 30 + x] = acc3[mi][reg] + obv;
                }
            }
        }
    }
}

// ---------------------------------------------------------------------------
extern "C" void kernel_launch(void* const* d_in, const int* in_sizes, int n_in,
                              void* d_out, int out_size, void* d_ws, size_t ws_size,
                              hipStream_t stream) {
    const float* feat    = (const float*)d_in[0];
    const float* boxes   = (const float*)d_in[1];
    const int*   box_ids = (const int*)d_in[2];
    const int*   cls     = (const int*)d_in[3];
    const float* c1w     = (const float*)d_in[4];
    const float* c1b     = (const float*)d_in[5];
    const float* c2w     = (const float*)d_in[6];
    const float* c2b     = (const float*)d_in[7];
    const float* ow      = (const float*)d_in[8];
    const float* ob      = (const float*)d_in[9];

    unsigned short* wt1  = (unsigned short*)d_ws;
    unsigned short* wt2  = wt1 + 36864;
    unsigned short* wto  = wt2 + 36864;

    wprep_kernel<<<324, 256, 0, stream>>>(c1w, c2w, ow, wt1, wt2, wto);
    mega_kernel<<<dim3(4, NB), 512, 0, stream>>>(feat, boxes, box_ids,
                                                 wt1, c1b, wt2, c2b, wto, ob,
                                                 cls, (float*)d_out);
}

// Round 11
// 450.423 us; speedup vs baseline: 1.0328x; 1.0328x over previous
//
#include <hip/hip_runtime.h>

#define HH 192
#define WW 192
#define CC 64
#define NB 1024
#define SS 32

typedef __bf16 bf16x8 __attribute__((ext_vector_type(8)));
typedef float  f32x4  __attribute__((ext_vector_type(4)));

__device__ __forceinline__ unsigned short f2bf(float f) {
    unsigned int u = __builtin_bit_cast(unsigned int, f);
    u += 0x7FFFu + ((u >> 16) & 1u);   // round-to-nearest-even
    return (unsigned short)(u >> 16);
}

// ---------------------------------------------------------------------------
// Merged weight prep (single launch, 324 blocks x 256 thr):
//  blocks [0,144): conv1 w -> WT1;  [144,288): conv2 w -> WT2;
//  blocks [288,324): out w -> WTo (cols padded to 16).
// WT[tap][kc][nt][lane][j], c = kc*32 + (lane>>4)*8 + j, o = nt*16 + (lane&15)
// ---------------------------------------------------------------------------
__global__ __launch_bounds__(256) void wprep_kernel(
        const float* __restrict__ c1w, const float* __restrict__ c2w,
        const float* __restrict__ ow, unsigned short* __restrict__ wt1,
        unsigned short* __restrict__ wt2, unsigned short* __restrict__ wto) {
    int b = blockIdx.x;
    if (b < 288) {
        const float* w = (b < 144) ? c1w : c2w;
        unsigned short* wt = (b < 144) ? wt1 : wt2;
        int idx = (b < 144 ? b : b - 144) * 256 + threadIdx.x;   // 0 .. 36863
        int j    = idx & 7;
        int lane = (idx >> 3) & 63;
        int nt   = (idx >> 9) & 3;
        int kc   = (idx >> 11) & 1;
        int tap  = idx >> 12;
        int c = kc * 32 + ((lane >> 4) << 3) + j;
        int o = (nt << 4) + (lane & 15);
        wt[idx] = f2bf(w[(tap * 64 + c) * 64 + o]);
    } else {
        int idx = (b - 288) * 256 + threadIdx.x;                 // 0 .. 9215
        int j    = idx & 7;
        int lane = (idx >> 3) & 63;
        int kc   = (idx >> 9) & 1;
        int tap  = idx >> 10;
        int c = kc * 32 + ((lane >> 4) << 3) + j;
        int o = lane & 15;
        wto[idx] = (o < 3) ? f2bf(ow[(tap * 64 + c) * 3 + o]) : (unsigned short)0;
    }
}

// ---------------------------------------------------------------------------
// FUSED crop + conv1: bilinear crop computed directly into LDS (halo rows
// included, 1.25x recompute), then 3x3 SAME conv 64->64 + ReLU via MFMA.
// Proven operating point (round 4, 140 us): pad-72 LDS (46080 B, 3 blk/CU),
// scattered 2B epilogue stores. UNTOUCHED.
// ---------------------------------------------------------------------------
__global__ __launch_bounds__(256, 3) void crop_conv1_kernel(
        const float* __restrict__ feat, const float* __restrict__ boxes,
        const int* __restrict__ box_ids, const unsigned short* __restrict__ wt,
        const float* __restrict__ bias, unsigned short* __restrict__ out, int n0) {
    __shared__ unsigned short s_in[10 * 32 * 72];   // 46080 B -> 3 blocks/CU

    int nl = blockIdx.y;
    int gn = n0 + nl;
    int y0 = blockIdx.x << 3;
    int t = threadIdx.x;
    int wave = t >> 6, lane = t & 63;
    int quad = lane >> 4, mcol = lane & 15;

    // ---- crop stage: rows y0-1 .. y0+8 (zeros outside [0,32)) ----
    {
        int px = t >> 3, cg = t & 7, c0 = cg << 3;
        float by1 = boxes[gn * 4 + 0];
        float bx1 = boxes[gn * 4 + 1];
        float by2 = boxes[gn * 4 + 2];
        float bx2 = boxes[gn * 4 + 3];
        float tx = (float)px / 31.0f;
        float xs = (bx1 + tx * (bx2 - bx1)) * 191.0f;
        float x0f = fminf(fmaxf(floorf(xs), 0.0f), 191.0f);
        float wx = xs - x0f;
        int x0i = (int)x0f, x1i = min(x0i + 1, 191);
        const float* fb = feat + (size_t)box_ids[gn] * (HH * WW * CC);
        unsigned short* dst = s_in + px * 72 + c0;
#pragma unroll 2
        for (int r = 0; r < 10; r++) {
            int gy = y0 + r - 1;
            uint4 v = {0, 0, 0, 0};
            if (gy >= 0 && gy < 32) {
                float ty = (float)gy / 31.0f;
                float ys = (by1 + ty * (by2 - by1)) * 191.0f;
                float y0f = fminf(fmaxf(floorf(ys), 0.0f), 191.0f);
                float wy = ys - y0f;
                int y0i = (int)y0f, y1i = min(y0i + 1, 191);
                const float* p00 = fb + ((size_t)y0i * WW + x0i) * CC + c0;
                const float* p01 = fb + ((size_t)y0i * WW + x1i) * CC + c0;
                const float* p10 = fb + ((size_t)y1i * WW + x0i) * CC + c0;
                const float* p11 = fb + ((size_t)y1i * WW + x1i) * CC + c0;
                unsigned int rr[4];
#pragma unroll
                for (int h = 0; h < 2; h++) {
                    float4 v00 = *(const float4*)(p00 + 4 * h);
                    float4 v01 = *(const float4*)(p01 + 4 * h);
                    float4 v10 = *(const float4*)(p10 + 4 * h);
                    float4 v11 = *(const float4*)(p11 + 4 * h);
                    const float* a00 = (const float*)&v00;
                    const float* a01 = (const float*)&v01;
                    const float* a10 = (const float*)&v10;
                    const float* a11 = (const float*)&v11;
#pragma unroll
                    for (int i = 0; i < 4; i++) {
                        float top = a00[i] + wx * (a01[i] - a00[i]);
                        float bot = a10[i] + wx * (a11[i] - a10[i]);
                        float val = top + wy * (bot - top);
                        unsigned short bb = f2bf(val);
                        int e = 4 * h + i;
                        if (e & 1) rr[e >> 1] |= ((unsigned int)bb << 16);
                        else       rr[e >> 1]  = (unsigned int)bb;
                    }
                }
                v = *(uint4*)rr;
            }
            *(uint4*)(dst + r * 32 * 72) = v;
        }
    }
    __syncthreads();

    // ---- conv1 MFMA ----
    f32x4 acc[4][4];
#pragma unroll
    for (int nt = 0; nt < 4; nt++) {
        float bv = bias[(nt << 4) + mcol];
#pragma unroll
        for (int mi = 0; mi < 4; mi++) acc[mi][nt] = (f32x4){bv, bv, bv, bv};
    }

    int r0 = wave << 1;
#pragma unroll
    for (int dy = 0; dy < 3; dy++) {
#pragma unroll
        for (int dx = 0; dx < 3; dx++) {
            int tap = dy * 3 + dx;
#pragma unroll
            for (int kc = 0; kc < 2; kc++) {
                uint4 bfr[4];
#pragma unroll
                for (int nt = 0; nt < 4; nt++)
                    bfr[nt] = *(const uint4*)(wt + ((((tap * 2 + kc) * 4 + nt) * 64 + lane) << 3));
                uint4 afr[4];
#pragma unroll
                for (int mi = 0; mi < 4; mi++) {
                    int xs = ((mi & 1) << 4) + mcol + dx - 1;
                    uint4 a = {0, 0, 0, 0};
                    if (xs >= 0 && xs < 32)
                        a = *(const uint4*)(s_in + ((r0 + (mi >> 1) + dy) * 32 + xs) * 72 +
                                            (kc << 5) + (quad << 3));
                    afr[mi] = a;
                }
#pragma unroll
                for (int mi = 0; mi < 4; mi++)
#pragma unroll
                    for (int nt = 0; nt < 4; nt++)
                        acc[mi][nt] = __builtin_amdgcn_mfma_f32_16x16x32_bf16(
                            __builtin_bit_cast(bf16x8, afr[mi]),
                            __builtin_bit_cast(bf16x8, bfr[nt]), acc[mi][nt], 0, 0, 0);
            }
        }
    }

    // epilogue: scattered 2B stores (no write amplification at 3 blk/CU)
#pragma unroll
    for (int mi = 0; mi < 4; mi++) {
        int yy = y0 + r0 + (mi >> 1);
        int xb = ((mi & 1) << 4) + (quad << 2);
#pragma unroll
        for (int reg = 0; reg < 4; reg++) {
            unsigned short* op = out + (((size_t)nl * 32 + yy) * 32 + (xb + reg)) * 64 + mcol;
#pragma unroll
            for (int nt = 0; nt < 4; nt++) {
                float v = fmaxf(acc[mi][nt][reg], 0.0f);
                op[nt << 4] = f2bf(v);
            }
        }
    }
}

// ---------------------------------------------------------------------------
// FUSED conv2 + outconv — r7 structure at 384 threads / 6 waves.
// LDS [12][32][64] swizzled + pad -> 57344 B -> 2 blocks/CU (the L3-safe
// concurrent-block count, rounds 5/6/7), now 12 waves/CU (3/SIMD) for
// latency hiding. Worst-phase VGPR ~110 (acc[4][4]) << the 170 budget at
// 3 waves/SIMD — avoids r8's spill (acc[5][4] under a 128 cap).
//   stage: 12 rows of conv1 act, 8 uint4 copies per thread (3072 = 8*384)
//   conv2: 20 m-tiles, mt = wave + 6i (i<4, guard mt<20, wave-uniform)
//   write-back: same mapping, into s_in rows 0..9
//   outconv: 16 (row,half)-tiles, mt = wave + 6i (i<3, guard mt<16)
// ---------------------------------------------------------------------------
#define S_IN_ELEMS (12 * 32 * 64)
__global__ __launch_bounds__(384, 2) void conv2_out_kernel(
        const unsigned short* __restrict__ in, const unsigned short* __restrict__ wt,
        const float* __restrict__ bias, const unsigned short* __restrict__ wto,
        const float* __restrict__ ob, const int* __restrict__ cls,
        float* __restrict__ out, int n0) {
    // 49152 B used + 8192 B pad = 57344 B -> exactly 2 blocks/CU
    __shared__ unsigned short s_in[S_IN_ELEMS + 4096];

    int nl = blockIdx.y;
    int y0 = blockIdx.x << 3;
    int t = threadIdx.x;
    int wave = t >> 6, lane = t & 63;
    int quad = lane >> 4, mcol = lane & 15;

    // ---- stage conv1 rows y0-1 .. y0+10 (zeros outside [0,32)), swizzled.
    //      3072 uint4 chunks spread over 384 threads (8 each). ----
    {
        const unsigned short* srcb = in + ((size_t)nl * 32) * 2048;
#pragma unroll
        for (int i = 0; i < 8; i++) {
            int linear = i * 384 + t;            // 0 .. 3071
            int r = linear >> 8;                 // 0 .. 11
            int pair = linear & 255;
            int px = pair >> 3, cg = pair & 7;
            int gy = y0 + r - 1;
            uint4 v = {0, 0, 0, 0};
            if (gy >= 0 && gy < 32)
                v = *(const uint4*)(srcb + ((size_t)gy * 32 + px) * 64 + (cg << 3));
            *(uint4*)(s_in + (r << 11) + (px << 6) + ((cg ^ (px & 7)) << 3)) = v;
        }
    }
    __syncthreads();

    // ---- conv2 (SAME, 64->64): 20 m-tiles (lr = mt>>1, col-half h = mt&1);
    //      wave w handles mt = w + 6i, i = 0..3 (guard mt<20, wave-uniform) ----
    float bv[4];
#pragma unroll
    for (int nt = 0; nt < 4; nt++) bv[nt] = bias[(nt << 4) + mcol];

    f32x4 acc[4][4];
#pragma unroll
    for (int i = 0; i < 4; i++)
#pragma unroll
        for (int nt = 0; nt < 4; nt++)
            acc[i][nt] = (f32x4){bv[nt], bv[nt], bv[nt], bv[nt]};

#pragma unroll
    for (int dy = 0; dy < 3; dy++) {
#pragma unroll
        for (int dx = 0; dx < 3; dx++) {
            int tap = dy * 3 + dx;
#pragma unroll
            for (int kc = 0; kc < 2; kc++) {
                int cslot = (kc << 2) + quad;
                uint4 bfr[4];
#pragma unroll
                for (int nt = 0; nt < 4; nt++)
                    bfr[nt] = *(const uint4*)(wt + ((((tap * 2 + kc) * 4 + nt) * 64 + lane) << 3));
#pragma unroll
                for (int i = 0; i < 4; i++) {
                    int mt = wave + i * 6;
                    if (mt < 20) {                    // wave-uniform
                        int lr = mt >> 1, h = mt & 1;
                        int xs = (h << 4) + mcol + dx - 1;
                        uint4 a = {0, 0, 0, 0};
                        if (xs >= 0 && xs < 32)
                            a = *(const uint4*)(s_in + (((lr + dy) * 32 + xs) << 6) +
                                                ((cslot ^ (xs & 7)) << 3));
#pragma unroll
                        for (int nt = 0; nt < 4; nt++)
                            acc[i][nt] = __builtin_amdgcn_mfma_f32_16x16x32_bf16(
                                __builtin_bit_cast(bf16x8, a),
                                __builtin_bit_cast(bf16x8, bfr[nt]), acc[i][nt], 0, 0, 0);
                    }
                }
            }
        }
    }
    __syncthreads();   // all conv2 LDS reads done; safe to repurpose s_in

    // ---- write ReLU'd conv2 bf16 into s_in rows 0..9 (swizzled) ----
#pragma unroll
    for (int i = 0; i < 4; i++) {
        int mt = wave + i * 6;
        if (mt < 20) {
            int lr = mt >> 1, h = mt & 1;
            int xb = (h << 4) + (quad << 2);
#pragma unroll
            for (int reg = 0; reg < 4; reg++) {
                int px = xb + reg;
#pragma unroll
                for (int nt = 0; nt < 4; nt++) {
                    int oc = (nt << 4) + mcol;
                    float v = fmaxf(acc[i][nt][reg], 0.0f);
                    s_in[((lr * 32 + px) << 6) + (((oc >> 3) ^ (px & 7)) << 3) + (oc & 7)] = f2bf(v);
                }
            }
        }
    }
    __syncthreads();

    // ---- outconv (VALID, 64->3 padded 16): 16 (row,half)-tiles,
    //      wave w handles mt = w + 6i, i = 0..2 (guard mt<16) ----
    f32x4 acc2[3];
#pragma unroll
    for (int i = 0; i < 3; i++) acc2[i] = (f32x4){0.f, 0.f, 0.f, 0.f};

#pragma unroll
    for (int dy = 0; dy < 3; dy++) {
#pragma unroll
        for (int dx = 0; dx < 3; dx++) {
            int tap = dy * 3 + dx;
#pragma unroll
            for (int kc = 0; kc < 2; kc++) {
                int cslot = (kc << 2) + quad;
                uint4 bfr = *(const uint4*)(wto + (((tap * 2 + kc) * 64 + lane) << 3));
#pragma unroll
                for (int i = 0; i < 3; i++) {
                    int mt = wave + i * 6;
                    if (mt < 16) {                    // wave-uniform
                        int orow = mt >> 1, h = mt & 1;
                        int xs = (h << 4) + mcol + dx;    // VALID: 0..33
                        if (xs > 31) xs = 31;             // clamped lanes feed x>=30 (discarded)
                        uint4 a = *(const uint4*)(s_in + (((orow + dy) * 32 + xs) << 6) +
                                                  ((cslot ^ (xs & 7)) << 3));
                        acc2[i] = __builtin_amdgcn_mfma_f32_16x16x32_bf16(
                            __builtin_bit_cast(bf16x8, a),
                            __builtin_bit_cast(bf16x8, bfr), acc2[i], 0, 0, 0);
                    }
                }
            }
        }
    }

    int gn = n0 + nl;
    int oc = cls[gn];
    if (mcol == oc) {
        float obv = ob[oc];
#pragma unroll
        for (int i = 0; i < 3; i++) {
            int mt = wave + i * 6;
            if (mt < 16) {
                int orow = mt >> 1, h = mt & 1;
                int yy = y0 + orow;
                int xb = (h << 4) + (quad << 2);
                if (yy < 30) {
#pragma unroll
                    for (int reg = 0; reg < 4; reg++) {
                        int x = xb + reg;
                        if (x < 30)
                            out[(size_t)gn * 900 + yy * 30 + x] = acc2[i][reg] + obv;
                    }
                }
            }
        }
    }
}

// ---------------------------------------------------------------------------
extern "C" void kernel_launch(void* const* d_in, const int* in_sizes, int n_in,
                              void* d_out, int out_size, void* d_ws, size_t ws_size,
                              hipStream_t stream) {
    const float* feat    = (const float*)d_in[0];
    const float* boxes   = (const float*)d_in[1];
    const int*   box_ids = (const int*)d_in[2];
    const int*   cls     = (const int*)d_in[3];
    const float* c1w     = (const float*)d_in[4];
    const float* c1b     = (const float*)d_in[5];
    const float* c2w     = (const float*)d_in[6];
    const float* c2b     = (const float*)d_in[7];
    const float* ow      = (const float*)d_in[8];
    const float* ob      = (const float*)d_in[9];

    unsigned short* wt1  = (unsigned short*)d_ws;
    unsigned short* wt2  = wt1 + 36864;
    unsigned short* wto  = wt2 + 36864;
    unsigned short* bufA = wto + 9216;

    // single bf16 [nc][32][32][64] buffer in ws; nc as large as fits (pref 1024)
    size_t wt_bytes = (size_t)(36864 * 2 + 9216) * 2;
    size_t avail = (ws_size > wt_bytes) ? (ws_size - wt_bytes) : 0;
    size_t per_box = (size_t)32 * 32 * 64 * 2;
    int nc = (int)(avail / per_box);
    if (nc >= NB) nc = NB;
    else {
        int p = 1;
        while (p * 2 <= nc) p *= 2;
        nc = (p < 1) ? 1 : p;
    }

    wprep_kernel<<<324, 256, 0, stream>>>(c1w, c2w, ow, wt1, wt2, wto);

    for (int nn0 = 0; nn0 < NB; nn0 += nc) {
        int cur = (NB - nn0 < nc) ? (NB - nn0) : nc;
        crop_conv1_kernel<<<dim3(4, cur), 256, 0, stream>>>(feat, boxes, box_ids,
                                                            wt1, c1b, bufA, nn0);
        conv2_out_kernel<<<dim3(4, cur), 384, 0, stream>>>(bufA, wt2, c2b, wto, ob,
                                                           cls, (float*)d_out, nn0);
    }
}

// Round 12
// 358.965 us; speedup vs baseline: 1.2959x; 1.2548x over previous
//
#include <hip/hip_runtime.h>

#define HH 192
#define WW 192
#define CC 64
#define NB 1024
#define SS 32

typedef __bf16 bf16x8 __attribute__((ext_vector_type(8)));
typedef float  f32x4  __attribute__((ext_vector_type(4)));

__device__ __forceinline__ unsigned short f2bf(float f) {
    unsigned int u = __builtin_bit_cast(unsigned int, f);
    u += 0x7FFFu + ((u >> 16) & 1u);   // round-to-nearest-even
    return (unsigned short)(u >> 16);
}

// ---------------------------------------------------------------------------
// Merged weight prep (single launch, 324 blocks x 256 thr):
//  blocks [0,144): conv1 w -> WT1;  [144,288): conv2 w -> WT2;
//  blocks [288,324): out w -> WTo (cols padded to 16).
// WT[tap][kc][nt][lane][j], c = kc*32 + (lane>>4)*8 + j, o = nt*16 + (lane&15)
// ---------------------------------------------------------------------------
__global__ __launch_bounds__(256) void wprep_kernel(
        const float* __restrict__ c1w, const float* __restrict__ c2w,
        const float* __restrict__ ow, unsigned short* __restrict__ wt1,
        unsigned short* __restrict__ wt2, unsigned short* __restrict__ wto) {
    int b = blockIdx.x;
    if (b < 288) {
        const float* w = (b < 144) ? c1w : c2w;
        unsigned short* wt = (b < 144) ? wt1 : wt2;
        int idx = (b < 144 ? b : b - 144) * 256 + threadIdx.x;   // 0 .. 36863
        int j    = idx & 7;
        int lane = (idx >> 3) & 63;
        int nt   = (idx >> 9) & 3;
        int kc   = (idx >> 11) & 1;
        int tap  = idx >> 12;
        int c = kc * 32 + ((lane >> 4) << 3) + j;
        int o = (nt << 4) + (lane & 15);
        wt[idx] = f2bf(w[(tap * 64 + c) * 64 + o]);
    } else {
        int idx = (b - 288) * 256 + threadIdx.x;                 // 0 .. 9215
        int j    = idx & 7;
        int lane = (idx >> 3) & 63;
        int kc   = (idx >> 9) & 1;
        int tap  = idx >> 10;
        int c = kc * 32 + ((lane >> 4) << 3) + j;
        int o = lane & 15;
        wto[idx] = (o < 3) ? f2bf(ow[(tap * 64 + c) * 3 + o]) : (unsigned short)0;
    }
}

// ---------------------------------------------------------------------------
// FUSED crop + conv1. Swizzled zero-conflict LDS ([10][32][64], slot =
// cg ^ (px&7), layout proven correct in r2) with the ALLOCATION padded to
// 46080 B so residency stays 3 blocks/CU (r2's regression was the 4-blk/CU
// traffic explosion, not the layout — r7 proved the two decouple).
// Scattered 2B epilogue stores (proven no write amplification at 3 blk/CU).
// ---------------------------------------------------------------------------
#define CROP_ELEMS (10 * 32 * 64)
__global__ __launch_bounds__(256, 3) void crop_conv1_kernel(
        const float* __restrict__ feat, const float* __restrict__ boxes,
        const int* __restrict__ box_ids, const unsigned short* __restrict__ wt,
        const float* __restrict__ bias, unsigned short* __restrict__ out, int n0) {
    // 40960 B used + 5120 B pad = 46080 B -> exactly 3 blocks/CU
    __shared__ unsigned short s_in[CROP_ELEMS + 2560];

    int nl = blockIdx.y;
    int gn = n0 + nl;
    int y0 = blockIdx.x << 3;
    int t = threadIdx.x;
    int wave = t >> 6, lane = t & 63;
    int quad = lane >> 4, mcol = lane & 15;

    // ---- crop stage: rows y0-1 .. y0+8 (zeros outside [0,32)), swizzled ----
    {
        int px = t >> 3, cg = t & 7, c0 = cg << 3;
        float by1 = boxes[gn * 4 + 0];
        float bx1 = boxes[gn * 4 + 1];
        float by2 = boxes[gn * 4 + 2];
        float bx2 = boxes[gn * 4 + 3];
        float tx = (float)px / 31.0f;
        float xs = (bx1 + tx * (bx2 - bx1)) * 191.0f;
        float x0f = fminf(fmaxf(floorf(xs), 0.0f), 191.0f);
        float wx = xs - x0f;
        int x0i = (int)x0f, x1i = min(x0i + 1, 191);
        const float* fb = feat + (size_t)box_ids[gn] * (HH * WW * CC);
        unsigned short* dst = s_in + (px << 6) + ((cg ^ (px & 7)) << 3);
#pragma unroll 2
        for (int r = 0; r < 10; r++) {
            int gy = y0 + r - 1;
            uint4 v = {0, 0, 0, 0};
            if (gy >= 0 && gy < 32) {
                float ty = (float)gy / 31.0f;
                float ys = (by1 + ty * (by2 - by1)) * 191.0f;
                float y0f = fminf(fmaxf(floorf(ys), 0.0f), 191.0f);
                float wy = ys - y0f;
                int y0i = (int)y0f, y1i = min(y0i + 1, 191);
                const float* p00 = fb + ((size_t)y0i * WW + x0i) * CC + c0;
                const float* p01 = fb + ((size_t)y0i * WW + x1i) * CC + c0;
                const float* p10 = fb + ((size_t)y1i * WW + x0i) * CC + c0;
                const float* p11 = fb + ((size_t)y1i * WW + x1i) * CC + c0;
                unsigned int rr[4];
#pragma unroll
                for (int h = 0; h < 2; h++) {
                    float4 v00 = *(const float4*)(p00 + 4 * h);
                    float4 v01 = *(const float4*)(p01 + 4 * h);
                    float4 v10 = *(const float4*)(p10 + 4 * h);
                    float4 v11 = *(const float4*)(p11 + 4 * h);
                    const float* a00 = (const float*)&v00;
                    const float* a01 = (const float*)&v01;
                    const float* a10 = (const float*)&v10;
                    const float* a11 = (const float*)&v11;
#pragma unroll
                    for (int i = 0; i < 4; i++) {
                        float top = a00[i] + wx * (a01[i] - a00[i]);
                        float bot = a10[i] + wx * (a11[i] - a10[i]);
                        float val = top + wy * (bot - top);
                        unsigned short bb = f2bf(val);
                        int e = 4 * h + i;
                        if (e & 1) rr[e >> 1] |= ((unsigned int)bb << 16);
                        else       rr[e >> 1]  = (unsigned int)bb;
                    }
                }
                v = *(uint4*)rr;
            }
            *(uint4*)(dst + (r << 11)) = v;
        }
    }
    __syncthreads();

    // ---- conv1 MFMA (swizzled a-frag reads, zero-conflict) ----
    f32x4 acc[4][4];
#pragma unroll
    for (int nt = 0; nt < 4; nt++) {
        float bv = bias[(nt << 4) + mcol];
#pragma unroll
        for (int mi = 0; mi < 4; mi++) acc[mi][nt] = (f32x4){bv, bv, bv, bv};
    }

    int r0 = wave << 1;
#pragma unroll
    for (int dy = 0; dy < 3; dy++) {
#pragma unroll
        for (int dx = 0; dx < 3; dx++) {
            int tap = dy * 3 + dx;
#pragma unroll
            for (int kc = 0; kc < 2; kc++) {
                int cslot = (kc << 2) + quad;
                uint4 bfr[4];
#pragma unroll
                for (int nt = 0; nt < 4; nt++)
                    bfr[nt] = *(const uint4*)(wt + ((((tap * 2 + kc) * 4 + nt) * 64 + lane) << 3));
                uint4 afr[4];
#pragma unroll
                for (int mi = 0; mi < 4; mi++) {
                    int xs = ((mi & 1) << 4) + mcol + dx - 1;
                    uint4 a = {0, 0, 0, 0};
                    if (xs >= 0 && xs < 32)
                        a = *(const uint4*)(s_in + (((r0 + (mi >> 1) + dy) * 32 + xs) << 6) +
                                            ((cslot ^ (xs & 7)) << 3));
                    afr[mi] = a;
                }
#pragma unroll
                for (int mi = 0; mi < 4; mi++)
#pragma unroll
                    for (int nt = 0; nt < 4; nt++)
                        acc[mi][nt] = __builtin_amdgcn_mfma_f32_16x16x32_bf16(
                            __builtin_bit_cast(bf16x8, afr[mi]),
                            __builtin_bit_cast(bf16x8, bfr[nt]), acc[mi][nt], 0, 0, 0);
            }
        }
    }

    // epilogue: scattered 2B stores (no write amplification at 3 blk/CU)
#pragma unroll
    for (int mi = 0; mi < 4; mi++) {
        int yy = y0 + r0 + (mi >> 1);
        int xb = ((mi & 1) << 4) + (quad << 2);
#pragma unroll
        for (int reg = 0; reg < 4; reg++) {
            unsigned short* op = out + (((size_t)nl * 32 + yy) * 32 + (xb + reg)) * 64 + mcol;
#pragma unroll
            for (int nt = 0; nt < 4; nt++) {
                float v = fmaxf(acc[mi][nt][reg], 0.0f);
                op[nt << 4] = f2bf(v);
            }
        }
    }
}

// ---------------------------------------------------------------------------
// FUSED conv2 + outconv — ROUND-7 PROVEN VERSION, VERBATIM (147 us, VGPR=108,
// hbm 96 MB). 256 threads / 4 waves (r8/r11: any other wave count spills).
// Swizzled zero-conflict LDS ([12][32][64]) padded to 57344 B -> 2 blocks/CU.
// ---------------------------------------------------------------------------
#define S_IN_ELEMS (12 * 32 * 64)
__global__ __launch_bounds__(256, 2) void conv2_out_kernel(
        const unsigned short* __restrict__ in, const unsigned short* __restrict__ wt,
        const float* __restrict__ bias, const unsigned short* __restrict__ wto,
        const float* __restrict__ ob, const int* __restrict__ cls,
        float* __restrict__ out, int n0) {
    // 49152 B used + 8192 B pad = 57344 B -> exactly 2 blocks/CU
    __shared__ unsigned short s_in[S_IN_ELEMS + 4096];

    int nl = blockIdx.y;
    int y0 = blockIdx.x << 3;
    int t = threadIdx.x;
    int wave = t >> 6, lane = t & 63;
    int quad = lane >> 4, mcol = lane & 15;

    // ---- stage conv1 rows y0-1 .. y0+10 (zeros outside [0,32)), swizzled ----
    {
        int px = t >> 3, cg = t & 7;
        const unsigned short* src = in + (((size_t)nl * 32) * 32 + px) * 64 + (cg << 3);
        unsigned short* dst = s_in + (px << 6) + ((cg ^ (px & 7)) << 3);
#pragma unroll
        for (int r = 0; r < 12; r++) {
            int gy = y0 + r - 1;
            uint4 v = {0, 0, 0, 0};
            if (gy >= 0 && gy < 32) v = *(const uint4*)(src + (size_t)gy * 2048);
            *(uint4*)(dst + (r << 11)) = v;
        }
    }
    __syncthreads();

    // ---- conv2 (SAME, 64->64): 20 m-tiles = 10 rows x 2 col-halves;
    //      wave w handles mt = 5w .. 5w+4 (lr = mt>>1, col-half h = mt&1) ----
    float bv[4];
#pragma unroll
    for (int nt = 0; nt < 4; nt++) bv[nt] = bias[(nt << 4) + mcol];

    f32x4 acc[5][4];
#pragma unroll
    for (int i = 0; i < 5; i++)
#pragma unroll
        for (int nt = 0; nt < 4; nt++)
            acc[i][nt] = (f32x4){bv[nt], bv[nt], bv[nt], bv[nt]};

    int mt0 = wave * 5;
#pragma unroll
    for (int dy = 0; dy < 3; dy++) {
#pragma unroll
        for (int dx = 0; dx < 3; dx++) {
            int tap = dy * 3 + dx;
#pragma unroll
            for (int kc = 0; kc < 2; kc++) {
                int cslot = (kc << 2) + quad;
                uint4 bfr[4];
#pragma unroll
                for (int nt = 0; nt < 4; nt++)
                    bfr[nt] = *(const uint4*)(wt + ((((tap * 2 + kc) * 4 + nt) * 64 + lane) << 3));
#pragma unroll
                for (int i = 0; i < 5; i++) {
                    int mt = mt0 + i;
                    int lr = mt >> 1, h = mt & 1;
                    int xs = (h << 4) + mcol + dx - 1;
                    uint4 a = {0, 0, 0, 0};
                    if (xs >= 0 && xs < 32)
                        a = *(const uint4*)(s_in + (((lr + dy) * 32 + xs) << 6) +
                                            ((cslot ^ (xs & 7)) << 3));
#pragma unroll
                    for (int nt = 0; nt < 4; nt++)
                        acc[i][nt] = __builtin_amdgcn_mfma_f32_16x16x32_bf16(
                            __builtin_bit_cast(bf16x8, a),
                            __builtin_bit_cast(bf16x8, bfr[nt]), acc[i][nt], 0, 0, 0);
                }
            }
        }
    }
    __syncthreads();   // all conv2 LDS reads done; safe to repurpose s_in

    // ---- write ReLU'd conv2 bf16 into s_in rows 0..9 (swizzled) ----
#pragma unroll
    for (int i = 0; i < 5; i++) {
        int mt = mt0 + i;
        int lr = mt >> 1, h = mt & 1;
        int xb = (h << 4) + (quad << 2);
#pragma unroll
        for (int reg = 0; reg < 4; reg++) {
            int px = xb + reg;
#pragma unroll
            for (int nt = 0; nt < 4; nt++) {
                int oc = (nt << 4) + mcol;
                float v = fmaxf(acc[i][nt][reg], 0.0f);
                s_in[((lr * 32 + px) << 6) + (((oc >> 3) ^ (px & 7)) << 3) + (oc & 7)] = f2bf(v);
            }
        }
    }
    __syncthreads();

    // ---- outconv (VALID, 64->3 padded 16) from s_in rows 0..9 ----
    f32x4 acc2[4];
#pragma unroll
    for (int mi = 0; mi < 4; mi++) acc2[mi] = (f32x4){0.f, 0.f, 0.f, 0.f};

    int r0 = wave << 1;
#pragma unroll
    for (int dy = 0; dy < 3; dy++) {
#pragma unroll
        for (int dx = 0; dx < 3; dx++) {
            int tap = dy * 3 + dx;
#pragma unroll
            for (int kc = 0; kc < 2; kc++) {
                int cslot = (kc << 2) + quad;
                uint4 bfr = *(const uint4*)(wto + (((tap * 2 + kc) * 64 + lane) << 3));
#pragma unroll
                for (int mi = 0; mi < 4; mi++) {
                    int xs = ((mi & 1) << 4) + mcol + dx;     // VALID: 0..33
                    if (xs > 31) xs = 31;                     // clamped lanes feed x>=30 (discarded)
                    uint4 a = *(const uint4*)(s_in + (((r0 + (mi >> 1) + dy) * 32 + xs) << 6) +
                                              ((cslot ^ (xs & 7)) << 3));
                    acc2[mi] = __builtin_amdgcn_mfma_f32_16x16x32_bf16(
                        __builtin_bit_cast(bf16x8, a),
                        __builtin_bit_cast(bf16x8, bfr), acc2[mi], 0, 0, 0);
                }
            }
        }
    }

    int gn = n0 + nl;
    int oc = cls[gn];
    if (mcol == oc) {
        float obv = ob[oc];
#pragma unroll
        for (int mi = 0; mi < 4; mi++) {
            int yy = y0 + r0 + (mi >> 1);
            int xb = ((mi & 1) << 4) + (quad << 2);
            if (yy < 30) {
#pragma unroll
                for (int reg = 0; reg < 4; reg++) {
                    int x = xb + reg;
                    if (x < 30)
                        out[(size_t)gn * 900 + yy * 30 + x] = acc2[mi][reg] + obv;
                }
            }
        }
    }
}

// ---------------------------------------------------------------------------
extern "C" void kernel_launch(void* const* d_in, const int* in_sizes, int n_in,
                              void* d_out, int out_size, void* d_ws, size_t ws_size,
                              hipStream_t stream) {
    const float* feat    = (const float*)d_in[0];
    const float* boxes   = (const float*)d_in[1];
    const int*   box_ids = (const int*)d_in[2];
    const int*   cls     = (const int*)d_in[3];
    const float* c1w     = (const float*)d_in[4];
    const float* c1b     = (const float*)d_in[5];
    const float* c2w     = (const float*)d_in[6];
    const float* c2b     = (const float*)d_in[7];
    const float* ow      = (const float*)d_in[8];
    const float* ob      = (const float*)d_in[9];

    unsigned short* wt1  = (unsigned short*)d_ws;
    unsigned short* wt2  = wt1 + 36864;
    unsigned short* wto  = wt2 + 36864;
    unsigned short* bufA = wto + 9216;

    // single bf16 [nc][32][32][64] buffer in ws; nc as large as fits (pref 1024)
    size_t wt_bytes = (size_t)(36864 * 2 + 9216) * 2;
    size_t avail = (ws_size > wt_bytes) ? (ws_size - wt_bytes) : 0;
    size_t per_box = (size_t)32 * 32 * 64 * 2;
    int nc = (int)(avail / per_box);
    if (nc >= NB) nc = NB;
    else {
        int p = 1;
        while (p * 2 <= nc) p *= 2;
        nc = (p < 1) ? 1 : p;
    }

    wprep_kernel<<<324, 256, 0, stream>>>(c1w, c2w, ow, wt1, wt2, wto);

    for (int nn0 = 0; nn0 < NB; nn0 += nc) {
        int cur = (NB - nn0 < nc) ? (NB - nn0) : nc;
        crop_conv1_kernel<<<dim3(4, cur), 256, 0, stream>>>(feat, boxes, box_ids,
                                                            wt1, c1b, bufA, nn0);
        conv2_out_kernel<<<dim3(4, cur), 256, 0, stream>>>(bufA, wt2, c2b, wto, ob,
                                                           cls, (float*)d_out, nn0);
    }
}

// Round 13
// 338.106 us; speedup vs baseline: 1.3759x; 1.0617x over previous
//
#include <hip/hip_runtime.h>

#define HH 192
#define WW 192
#define CC 64
#define NB 1024
#define SS 32

typedef __bf16 bf16x8 __attribute__((ext_vector_type(8)));
typedef float  f32x4  __attribute__((ext_vector_type(4)));

__device__ __forceinline__ unsigned short f2bf(float f) {
    unsigned int u = __builtin_bit_cast(unsigned int, f);
    u += 0x7FFFu + ((u >> 16) & 1u);   // round-to-nearest-even
    return (unsigned short)(u >> 16);
}

// Bijective XCD-chunked work mapping (T1, m204 form). total must be the grid
// size; maps dispatch id -> work id so each XCD gets a CONTIGUOUS work range
// (tiles of one box adjacent on one XCD -> halo/feat reuse hits that XCD's L2).
__device__ __forceinline__ int xcd_swizzle(int id, int total) {
    int q = total >> 3, r = total & 7;
    if (r == 0) return (id & 7) * q + (id >> 3);
    return id;   // non-multiple-of-8 fallback (not hit with our grids)
}

// ---------------------------------------------------------------------------
// Merged weight prep (single launch, 324 blocks x 256 thr):
//  blocks [0,144): conv1 w -> WT1;  [144,288): conv2 w -> WT2;
//  blocks [288,324): out w -> WTo (cols padded to 16).
// WT[tap][kc][nt][lane][j], c = kc*32 + (lane>>4)*8 + j, o = nt*16 + (lane&15)
// ---------------------------------------------------------------------------
__global__ __launch_bounds__(256) void wprep_kernel(
        const float* __restrict__ c1w, const float* __restrict__ c2w,
        const float* __restrict__ ow, unsigned short* __restrict__ wt1,
        unsigned short* __restrict__ wt2, unsigned short* __restrict__ wto) {
    int b = blockIdx.x;
    if (b < 288) {
        const float* w = (b < 144) ? c1w : c2w;
        unsigned short* wt = (b < 144) ? wt1 : wt2;
        int idx = (b < 144 ? b : b - 144) * 256 + threadIdx.x;   // 0 .. 36863
        int j    = idx & 7;
        int lane = (idx >> 3) & 63;
        int nt   = (idx >> 9) & 3;
        int kc   = (idx >> 11) & 1;
        int tap  = idx >> 12;
        int c = kc * 32 + ((lane >> 4) << 3) + j;
        int o = (nt << 4) + (lane & 15);
        wt[idx] = f2bf(w[(tap * 64 + c) * 64 + o]);
    } else {
        int idx = (b - 288) * 256 + threadIdx.x;                 // 0 .. 9215
        int j    = idx & 7;
        int lane = (idx >> 3) & 63;
        int kc   = (idx >> 9) & 1;
        int tap  = idx >> 10;
        int c = kc * 32 + ((lane >> 4) << 3) + j;
        int o = lane & 15;
        wto[idx] = (o < 3) ? f2bf(ow[(tap * 64 + c) * 3 + o]) : (unsigned short)0;
    }
}

// ---------------------------------------------------------------------------
// FUSED crop + conv1. Swizzled zero-conflict LDS ([10][32][64]) padded to
// 46080 B -> 3 blocks/CU (proven operating point). 1D grid + XCD-chunked
// work mapping: tiles of one box run on ONE XCD (L2 locality for feat + halo).
// ---------------------------------------------------------------------------
#define CROP_ELEMS (10 * 32 * 64)
__global__ __launch_bounds__(256, 3) void crop_conv1_kernel(
        const float* __restrict__ feat, const float* __restrict__ boxes,
        const int* __restrict__ box_ids, const unsigned short* __restrict__ wt,
        const float* __restrict__ bias, unsigned short* __restrict__ out,
        int n0, int nblk) {
    // 40960 B used + 5120 B pad = 46080 B -> exactly 3 blocks/CU
    __shared__ unsigned short s_in[CROP_ELEMS + 2560];

    int wid = xcd_swizzle(blockIdx.x, nblk);
    int nl = wid >> 2;
    int y0 = (wid & 3) << 3;
    int gn = n0 + nl;
    int t = threadIdx.x;
    int wave = t >> 6, lane = t & 63;
    int quad = lane >> 4, mcol = lane & 15;

    // ---- crop stage: rows y0-1 .. y0+8 (zeros outside [0,32)), swizzled ----
    {
        int px = t >> 3, cg = t & 7, c0 = cg << 3;
        float by1 = boxes[gn * 4 + 0];
        float bx1 = boxes[gn * 4 + 1];
        float by2 = boxes[gn * 4 + 2];
        float bx2 = boxes[gn * 4 + 3];
        float tx = (float)px / 31.0f;
        float xs = (bx1 + tx * (bx2 - bx1)) * 191.0f;
        float x0f = fminf(fmaxf(floorf(xs), 0.0f), 191.0f);
        float wx = xs - x0f;
        int x0i = (int)x0f, x1i = min(x0i + 1, 191);
        const float* fb = feat + (size_t)box_ids[gn] * (HH * WW * CC);
        unsigned short* dst = s_in + (px << 6) + ((cg ^ (px & 7)) << 3);
#pragma unroll 2
        for (int r = 0; r < 10; r++) {
            int gy = y0 + r - 1;
            uint4 v = {0, 0, 0, 0};
            if (gy >= 0 && gy < 32) {
                float ty = (float)gy / 31.0f;
                float ys = (by1 + ty * (by2 - by1)) * 191.0f;
                float y0f = fminf(fmaxf(floorf(ys), 0.0f), 191.0f);
                float wy = ys - y0f;
                int y0i = (int)y0f, y1i = min(y0i + 1, 191);
                const float* p00 = fb + ((size_t)y0i * WW + x0i) * CC + c0;
                const float* p01 = fb + ((size_t)y0i * WW + x1i) * CC + c0;
                const float* p10 = fb + ((size_t)y1i * WW + x0i) * CC + c0;
                const float* p11 = fb + ((size_t)y1i * WW + x1i) * CC + c0;
                unsigned int rr[4];
#pragma unroll
                for (int h = 0; h < 2; h++) {
                    float4 v00 = *(const float4*)(p00 + 4 * h);
                    float4 v01 = *(const float4*)(p01 + 4 * h);
                    float4 v10 = *(const float4*)(p10 + 4 * h);
                    float4 v11 = *(const float4*)(p11 + 4 * h);
                    const float* a00 = (const float*)&v00;
                    const float* a01 = (const float*)&v01;
                    const float* a10 = (const float*)&v10;
                    const float* a11 = (const float*)&v11;
#pragma unroll
                    for (int i = 0; i < 4; i++) {
                        float top = a00[i] + wx * (a01[i] - a00[i]);
                        float bot = a10[i] + wx * (a11[i] - a10[i]);
                        float val = top + wy * (bot - top);
                        unsigned short bb = f2bf(val);
                        int e = 4 * h + i;
                        if (e & 1) rr[e >> 1] |= ((unsigned int)bb << 16);
                        else       rr[e >> 1]  = (unsigned int)bb;
                    }
                }
                v = *(uint4*)rr;
            }
            *(uint4*)(dst + (r << 11)) = v;
        }
    }
    __syncthreads();

    // ---- conv1 MFMA (swizzled a-frag reads, zero-conflict) ----
    f32x4 acc[4][4];
#pragma unroll
    for (int nt = 0; nt < 4; nt++) {
        float bv = bias[(nt << 4) + mcol];
#pragma unroll
        for (int mi = 0; mi < 4; mi++) acc[mi][nt] = (f32x4){bv, bv, bv, bv};
    }

    int r0 = wave << 1;
#pragma unroll
    for (int dy = 0; dy < 3; dy++) {
#pragma unroll
        for (int dx = 0; dx < 3; dx++) {
            int tap = dy * 3 + dx;
#pragma unroll
            for (int kc = 0; kc < 2; kc++) {
                int cslot = (kc << 2) + quad;
                uint4 bfr[4];
#pragma unroll
                for (int nt = 0; nt < 4; nt++)
                    bfr[nt] = *(const uint4*)(wt + ((((tap * 2 + kc) * 4 + nt) * 64 + lane) << 3));
                uint4 afr[4];
#pragma unroll
                for (int mi = 0; mi < 4; mi++) {
                    int xs = ((mi & 1) << 4) + mcol + dx - 1;
                    uint4 a = {0, 0, 0, 0};
                    if (xs >= 0 && xs < 32)
                        a = *(const uint4*)(s_in + (((r0 + (mi >> 1) + dy) * 32 + xs) << 6) +
                                            ((cslot ^ (xs & 7)) << 3));
                    afr[mi] = a;
                }
#pragma unroll
                for (int mi = 0; mi < 4; mi++)
#pragma unroll
                    for (int nt = 0; nt < 4; nt++)
                        acc[mi][nt] = __builtin_amdgcn_mfma_f32_16x16x32_bf16(
                            __builtin_bit_cast(bf16x8, afr[mi]),
                            __builtin_bit_cast(bf16x8, bfr[nt]), acc[mi][nt], 0, 0, 0);
            }
        }
    }

    // epilogue: scattered 2B stores (no write amplification at 3 blk/CU)
#pragma unroll
    for (int mi = 0; mi < 4; mi++) {
        int yy = y0 + r0 + (mi >> 1);
        int xb = ((mi & 1) << 4) + (quad << 2);
#pragma unroll
        for (int reg = 0; reg < 4; reg++) {
            unsigned short* op = out + (((size_t)nl * 32 + yy) * 32 + (xb + reg)) * 64 + mcol;
#pragma unroll
            for (int nt = 0; nt < 4; nt++) {
                float v = fmaxf(acc[mi][nt][reg], 0.0f);
                op[nt << 4] = f2bf(v);
            }
        }
    }
}

// ---------------------------------------------------------------------------
// FUSED conv2 + outconv — r7 structure (256 thr / 4 waves, 57344 B -> 2 blk/CU,
// zero-conflict swizzled LDS), with the same XCD-chunked work mapping so the
// tiles of one box read their bufA slice from ONE XCD's L2.
// ---------------------------------------------------------------------------
#define S_IN_ELEMS (12 * 32 * 64)
__global__ __launch_bounds__(256, 2) void conv2_out_kernel(
        const unsigned short* __restrict__ in, const unsigned short* __restrict__ wt,
        const float* __restrict__ bias, const unsigned short* __restrict__ wto,
        const float* __restrict__ ob, const int* __restrict__ cls,
        float* __restrict__ out, int n0, int nblk) {
    // 49152 B used + 8192 B pad = 57344 B -> exactly 2 blocks/CU
    __shared__ unsigned short s_in[S_IN_ELEMS + 4096];

    int wid = xcd_swizzle(blockIdx.x, nblk);
    int nl = wid >> 2;
    int y0 = (wid & 3) << 3;
    int t = threadIdx.x;
    int wave = t >> 6, lane = t & 63;
    int quad = lane >> 4, mcol = lane & 15;

    // ---- stage conv1 rows y0-1 .. y0+10 (zeros outside [0,32)), swizzled ----
    {
        int px = t >> 3, cg = t & 7;
        const unsigned short* src = in + (((size_t)nl * 32) * 32 + px) * 64 + (cg << 3);
        unsigned short* dst = s_in + (px << 6) + ((cg ^ (px & 7)) << 3);
#pragma unroll
        for (int r = 0; r < 12; r++) {
            int gy = y0 + r - 1;
            uint4 v = {0, 0, 0, 0};
            if (gy >= 0 && gy < 32) v = *(const uint4*)(src + (size_t)gy * 2048);
            *(uint4*)(dst + (r << 11)) = v;
        }
    }
    __syncthreads();

    // ---- conv2 (SAME, 64->64): 20 m-tiles = 10 rows x 2 col-halves;
    //      wave w handles mt = 5w .. 5w+4 (lr = mt>>1, col-half h = mt&1) ----
    float bv[4];
#pragma unroll
    for (int nt = 0; nt < 4; nt++) bv[nt] = bias[(nt << 4) + mcol];

    f32x4 acc[5][4];
#pragma unroll
    for (int i = 0; i < 5; i++)
#pragma unroll
        for (int nt = 0; nt < 4; nt++)
            acc[i][nt] = (f32x4){bv[nt], bv[nt], bv[nt], bv[nt]};

    int mt0 = wave * 5;
#pragma unroll
    for (int dy = 0; dy < 3; dy++) {
#pragma unroll
        for (int dx = 0; dx < 3; dx++) {
            int tap = dy * 3 + dx;
#pragma unroll
            for (int kc = 0; kc < 2; kc++) {
                int cslot = (kc << 2) + quad;
                uint4 bfr[4];
#pragma unroll
                for (int nt = 0; nt < 4; nt++)
                    bfr[nt] = *(const uint4*)(wt + ((((tap * 2 + kc) * 4 + nt) * 64 + lane) << 3));
#pragma unroll
                for (int i = 0; i < 5; i++) {
                    int mt = mt0 + i;
                    int lr = mt >> 1, h = mt & 1;
                    int xs = (h << 4) + mcol + dx - 1;
                    uint4 a = {0, 0, 0, 0};
                    if (xs >= 0 && xs < 32)
                        a = *(const uint4*)(s_in + (((lr + dy) * 32 + xs) << 6) +
                                            ((cslot ^ (xs & 7)) << 3));
#pragma unroll
                    for (int nt = 0; nt < 4; nt++)
                        acc[i][nt] = __builtin_amdgcn_mfma_f32_16x16x32_bf16(
                            __builtin_bit_cast(bf16x8, a),
                            __builtin_bit_cast(bf16x8, bfr[nt]), acc[i][nt], 0, 0, 0);
                }
            }
        }
    }
    __syncthreads();   // all conv2 LDS reads done; safe to repurpose s_in

    // ---- write ReLU'd conv2 bf16 into s_in rows 0..9 (swizzled) ----
#pragma unroll
    for (int i = 0; i < 5; i++) {
        int mt = mt0 + i;
        int lr = mt >> 1, h = mt & 1;
        int xb = (h << 4) + (quad << 2);
#pragma unroll
        for (int reg = 0; reg < 4; reg++) {
            int px = xb + reg;
#pragma unroll
            for (int nt = 0; nt < 4; nt++) {
                int oc = (nt << 4) + mcol;
                float v = fmaxf(acc[i][nt][reg], 0.0f);
                s_in[((lr * 32 + px) << 6) + (((oc >> 3) ^ (px & 7)) << 3) + (oc & 7)] = f2bf(v);
            }
        }
    }
    __syncthreads();

    // ---- outconv (VALID, 64->3 padded 16) from s_in rows 0..9 ----
    f32x4 acc2[4];
#pragma unroll
    for (int mi = 0; mi < 4; mi++) acc2[mi] = (f32x4){0.f, 0.f, 0.f, 0.f};

    int r0 = wave << 1;
#pragma unroll
    for (int dy = 0; dy < 3; dy++) {
#pragma unroll
        for (int dx = 0; dx < 3; dx++) {
            int tap = dy * 3 + dx;
#pragma unroll
            for (int kc = 0; kc < 2; kc++) {
                int cslot = (kc << 2) + quad;
                uint4 bfr = *(const uint4*)(wto + (((tap * 2 + kc) * 64 + lane) << 3));
#pragma unroll
                for (int mi = 0; mi < 4; mi++) {
                    int xs = ((mi & 1) << 4) + mcol + dx;     // VALID: 0..33
                    if (xs > 31) xs = 31;                     // clamped lanes feed x>=30 (discarded)
                    uint4 a = *(const uint4*)(s_in + (((r0 + (mi >> 1) + dy) * 32 + xs) << 6) +
                                              ((cslot ^ (xs & 7)) << 3));
                    acc2[mi] = __builtin_amdgcn_mfma_f32_16x16x32_bf16(
                        __builtin_bit_cast(bf16x8, a),
                        __builtin_bit_cast(bf16x8, bfr), acc2[mi], 0, 0, 0);
                }
            }
        }
    }

    int gn = n0 + nl;
    int oc = cls[gn];
    if (mcol == oc) {
        float obv = ob[oc];
#pragma unroll
        for (int mi = 0; mi < 4; mi++) {
            int yy = y0 + r0 + (mi >> 1);
            int xb = ((mi & 1) << 4) + (quad << 2);
            if (yy < 30) {
#pragma unroll
                for (int reg = 0; reg < 4; reg++) {
                    int x = xb + reg;
                    if (x < 30)
                        out[(size_t)gn * 900 + yy * 30 + x] = acc2[mi][reg] + obv;
                }
            }
        }
    }
}

// ---------------------------------------------------------------------------
extern "C" void kernel_launch(void* const* d_in, const int* in_sizes, int n_in,
                              void* d_out, int out_size, void* d_ws, size_t ws_size,
                              hipStream_t stream) {
    const float* feat    = (const float*)d_in[0];
    const float* boxes   = (const float*)d_in[1];
    const int*   box_ids = (const int*)d_in[2];
    const int*   cls     = (const int*)d_in[3];
    const float* c1w     = (const float*)d_in[4];
    const float* c1b     = (const float*)d_in[5];
    const float* c2w     = (const float*)d_in[6];
    const float* c2b     = (const float*)d_in[7];
    const float* ow      = (const float*)d_in[8];
    const float* ob      = (const float*)d_in[9];

    unsigned short* wt1  = (unsigned short*)d_ws;
    unsigned short* wt2  = wt1 + 36864;
    unsigned short* wto  = wt2 + 36864;
    unsigned short* bufA = wto + 9216;

    // single bf16 [nc][32][32][64] buffer in ws; nc as large as fits (pref 1024)
    size_t wt_bytes = (size_t)(36864 * 2 + 9216) * 2;
    size_t avail = (ws_size > wt_bytes) ? (ws_size - wt_bytes) : 0;
    size_t per_box = (size_t)32 * 32 * 64 * 2;
    int nc = (int)(avail / per_box);
    if (nc >= NB) nc = NB;
    else {
        int p = 1;
        while (p * 2 <= nc) p *= 2;
        nc = (p < 1) ? 1 : p;
    }

    wprep_kernel<<<324, 256, 0, stream>>>(c1w, c2w, ow, wt1, wt2, wto);

    for (int nn0 = 0; nn0 < NB; nn0 += nc) {
        int cur = (NB - nn0 < nc) ? (NB - nn0) : nc;
        int nblk = 4 * cur;
        crop_conv1_kernel<<<nblk, 256, 0, stream>>>(feat, boxes, box_ids,
                                                    wt1, c1b, bufA, nn0, nblk);
        conv2_out_kernel<<<nblk, 256, 0, stream>>>(bufA, wt2, c2b, wto, ob,
                                                   cls, (float*)d_out, nn0, nblk);
    }
}